// Round 18
// baseline (165.455 us; speedup 1.0000x reference)
//
#include <hip/hip_runtime.h>

// ---------- types ----------
typedef __attribute__((ext_vector_type(4))) float float4_;
typedef __attribute__((ext_vector_type(4))) float f32x4;
typedef __attribute__((ext_vector_type(8))) int   i32x8;

#define NROWS 8192
#define NKEYS 16384
#define DDIM  256

// exp(x/T) == exp2(x * C_SC)
static constexpr float T_INV = (float)(1.0 / 0.07);
static constexpr float C_SC  = (float)(1.0 / (0.07 * 0.6931471805599453));

// ---------------------------------------------------------------------------
// Fragment-linear key layout (NO LDS, NO swizzle): key-group G = 16 keys.
// Byte address of the 32B B-fragment of (G, kk, lane):
//     G*4096 + kk*2048 + lane*32
// lane = l4*16 + l15 holds key (G*16 + l15), dims [kk*128 + l4*32, +32)
// — the 16x16x128 B operand convention verified r8-r15.
// prep writes it, gemm reads it (rule #21: one convention, both sides).
// ---------------------------------------------------------------------------

// ---------------------------------------------------------------------------
// Kernel 1: normalize rows; emit fp8 e4m3 (OCP, HW cvt):
//   qs8  [8192][256] fp8: normalized q scaled by C_SC (MFMA A), natural.
//   keys8: fragment-linear (above). Keys 0..8191 = q, 8192..16383 = g.
//   Pterm[row] = dot_f32(q,g)/T ; diagsub[row] = exp2 of fp8-level qq diag.
// Also zeroes S and out[0].
// ---------------------------------------------------------------------------
__global__ __launch_bounds__(256) void prep_kernel(
    const float* __restrict__ h, const float* __restrict__ g,
    unsigned int* __restrict__ qs8, unsigned int* __restrict__ keys8,
    float* __restrict__ Pterm, float* __restrict__ diagsub,
    float* __restrict__ S, float* __restrict__ out)
{
  const int row  = blockIdx.x * 4 + (threadIdx.x >> 6);
  const int lane = threadIdx.x & 63;       // 4 dims each
  float4_ hv = *((const float4_*)h + row * 64 + lane);
  float4_ gv = *((const float4_*)g + row * 64 + lane);

  float ssh = hv.x*hv.x + hv.y*hv.y + hv.z*hv.z + hv.w*hv.w;
  float ssg = gv.x*gv.x + gv.y*gv.y + gv.z*gv.z + gv.w*gv.w;
#pragma unroll
  for (int m = 1; m < 64; m <<= 1) {
    ssh += __shfl_xor(ssh, m);
    ssg += __shfl_xor(ssg, m);
  }
  const float sh = 1.0f / fmaxf(sqrtf(ssh), 1e-8f);
  const float sg = 1.0f / fmaxf(sqrtf(ssg), 1e-8f);

  float qn[4] = { hv.x*sh, hv.y*sh, hv.z*sh, hv.w*sh };
  float gn[4] = { gv.x*sg, gv.y*sg, gv.z*sg, gv.w*sg };

  float pd = qn[0]*gn[0] + qn[1]*gn[1] + qn[2]*gn[2] + qn[3]*gn[3];

  // fp8 packs (RNE, saturating). word_sel / byte_sel must be literals.
  int pq = __builtin_amdgcn_cvt_pk_fp8_f32(qn[0], qn[1], 0, 0);
  pq     = __builtin_amdgcn_cvt_pk_fp8_f32(qn[2], qn[3], pq, 1);
  int ps = __builtin_amdgcn_cvt_pk_fp8_f32(qn[0]*C_SC, qn[1]*C_SC, 0, 0);
  ps     = __builtin_amdgcn_cvt_pk_fp8_f32(qn[2]*C_SC, qn[3]*C_SC, ps, 1);
  int pg = __builtin_amdgcn_cvt_pk_fp8_f32(gn[0], gn[1], 0, 0);
  pg     = __builtin_amdgcn_cvt_pk_fp8_f32(gn[2], gn[3], pg, 1);

  float dd =
      __builtin_amdgcn_cvt_f32_fp8(ps, 0) * __builtin_amdgcn_cvt_f32_fp8(pq, 0)
    + __builtin_amdgcn_cvt_f32_fp8(ps, 1) * __builtin_amdgcn_cvt_f32_fp8(pq, 1)
    + __builtin_amdgcn_cvt_f32_fp8(ps, 2) * __builtin_amdgcn_cvt_f32_fp8(pq, 2)
    + __builtin_amdgcn_cvt_f32_fp8(ps, 3) * __builtin_amdgcn_cvt_f32_fp8(pq, 3);

#pragma unroll
  for (int m = 1; m < 64; m <<= 1) {
    pd += __shfl_xor(pd, m);
    dd += __shfl_xor(dd, m);
  }

  qs8[(size_t)row * 64 + lane] = (unsigned int)ps;   // natural, coalesced

  // fragment-linear key writes: this lane's dword = dims [lane*4, lane*4+4)
  // kk = lane>>5 ; l4 = (lane>>3)&3 ; inner byte = (lane&7)*4
  char* kb = (char*)keys8;
  const int foff = ((lane >> 5) << 11) + (((lane >> 3) & 3) << 9)
                 + ((lane & 7) << 2);
  {
    const int k = row;                     // q keys
    *(unsigned int*)(kb + (((size_t)(k >> 4)) << 12) + foff
                     + ((k & 15) << 5)) = (unsigned int)pq;
  }
  {
    const int k = NROWS + row;             // g keys
    *(unsigned int*)(kb + (((size_t)(k >> 4)) << 12) + foff
                     + ((k & 15) << 5)) = (unsigned int)pg;
  }

  if (lane == 0) {
    Pterm[row]   = pd * T_INV;
    diagsub[row] = __builtin_amdgcn_exp2f(dd);
    S[row]       = 0.0f;
    if (row == 0) out[0] = 0.0f;           // finalize accumulates atomically
  }
}

// ---------------------------------------------------------------------------
// Kernel 2: fused MX-fp8 GEMM (K=128/instr) + exp2 + row-sum — no LDS
// staging, no main-loop barriers (r13 structure), BM=64, 2 blocks/CU (r15).
// vs r15: EXPLICIT one-iteration B-prefetch. r15's null at 2x TLP +
// "all pipes ~30% busy, 40% dual-idle" isolates the stall to the per-
// iteration load->consume vmcnt wait (L1 thrash: 16 disjoint 128KB streams
// per CU make every load an L2 round-trip). Loads for group g+1 issue at
// the top of iteration g into named regs (static, rule #20); harvest+MFMA
// consume group g's regs loaded ~450cy earlier -> counted waitcnt is free.
// ---------------------------------------------------------------------------
__global__ __launch_bounds__(512, 4) void nce_gemm(
    const unsigned int* __restrict__ qs8,
    const unsigned int* __restrict__ keys8,
    float* __restrict__ S)
{
  __shared__ float sred[64];               // end-of-kernel reduce only

  const int tid  = threadIdx.x;
  const int wid  = tid >> 6;
  const int lane = tid & 63;
  const int l15  = lane & 15, l4 = lane >> 4;

  const int bid   = blockIdx.x;
  const int slice = bid & 3;               // constant per XCD
  const int mtile = bid >> 2;              // 0..127
  const int m0    = mtile * 64;            // all 8 waves share these 64 rows

  if (tid < 64) sred[tid] = 0.0f;

  // ---- A fragments: 4 mf x 2 kk x 32B ; K elem = kk*128 + l4*32 + j ----
  const char* qb = (const char*)qs8;
  i32x8 a8[4][2];
#pragma unroll
  for (int mf = 0; mf < 4; ++mf) {
    const char* rp = qb + (size_t)(m0 + mf * 16 + l15) * 256 + l4 * 32;
#pragma unroll
    for (int kk = 0; kk < 2; ++kk)
      a8[mf][kk] = *(const i32x8*)(rp + kk * 128);
  }

  const f32x4 zero4 = { 0.f, 0.f, 0.f, 0.f };
  f32x4 acc[4];
  float Sp[4][4] = {};                     // [mf][q] row-sums

  // wave's private key range: 512 keys = 32 groups of 16
  const char* kp = (const char*)keys8
      + (((size_t)(slice * 256 + wid * 32)) << 12) + (size_t)lane * 32;

  // ---- software pipeline: bc = current group's B, bn = next (prefetch) ----
  i32x8 bc0 = *(const i32x8*)(kp);
  i32x8 bc1 = *(const i32x8*)(kp + 2048);

  for (int g = 0; g < 32; ++g) {
    i32x8 bn0, bn1;
    if (g + 1 < 32) {                      // issue next group's loads FIRST
      bn0 = *(const i32x8*)(kp + ((size_t)(g + 1) << 12));
      bn1 = *(const i32x8*)(kp + ((size_t)(g + 1) << 12) + 2048);
    }

    if (g > 0) {                           // harvest prev group (VALU,
#pragma unroll                             //  independent of the loads)
      for (int mf = 0; mf < 4; ++mf)
#pragma unroll
        for (int q = 0; q < 4; ++q)
          Sp[mf][q] += __builtin_amdgcn_exp2f(acc[mf][q]);
    }

    // MFMAs consume bc (loaded one full iteration ago — latency hidden).
    // cbsz=0 (A fmt fp8 e4m3), blgp=0 (B fmt fp8), scales 127 = x1.0
#pragma unroll
    for (int mf = 0; mf < 4; ++mf) {
      f32x4 t = __builtin_amdgcn_mfma_scale_f32_16x16x128_f8f6f4(
          a8[mf][0], bc0, zero4, 0, 0, 0, 127, 0, 127);
      acc[mf] = __builtin_amdgcn_mfma_scale_f32_16x16x128_f8f6f4(
          a8[mf][1], bc1, t, 0, 0, 0, 127, 0, 127);
    }

    bc0 = bn0;                             // rotate pipeline (reg rename)
    bc1 = bn1;
  }
#pragma unroll
  for (int mf = 0; mf < 4; ++mf)           // last group's harvest
#pragma unroll
    for (int q = 0; q < 4; ++q)
      Sp[mf][q] += __builtin_amdgcn_exp2f(acc[mf][q]);

  // reduce across the 16 key-columns (lanes sharing l4)
#pragma unroll
  for (int mf = 0; mf < 4; ++mf)
#pragma unroll
    for (int q = 0; q < 4; ++q) {
      float v = Sp[mf][q];
      v += __shfl_xor(v, 1); v += __shfl_xor(v, 2);
      v += __shfl_xor(v, 4); v += __shfl_xor(v, 8);
      Sp[mf][q] = v;
    }

  // block-level reduce in LDS (8 waves share the same 64 rows), then
  // one global atomic per row (4 slices -> 4 atomics/row total).
  __syncthreads();                         // sred init visible
  if (l15 == 0) {
#pragma unroll
    for (int mf = 0; mf < 4; ++mf)
#pragma unroll
      for (int q = 0; q < 4; ++q)
        atomicAdd(&sred[mf * 16 + l4 * 4 + q], Sp[mf][q]);
  }
  __syncthreads();
  if (tid < 64) atomicAdd(&S[m0 + tid], sred[tid]);
}

// ---------------------------------------------------------------------------
// Kernel 3: loss partials -> atomicAdd(out). 32 blocks x 256 thr = 1 row/thr.
// ---------------------------------------------------------------------------
__global__ __launch_bounds__(256) void finalize_kernel(
    const float* __restrict__ S, const float* __restrict__ Pterm,
    const float* __restrict__ diagsub, float* __restrict__ out)
{
  const int i = blockIdx.x * 256 + threadIdx.x;
  float v = S[i] - diagsub[i];
  float acc = logf(fmaxf(v, 1e-20f)) - Pterm[i];
#pragma unroll
  for (int m = 1; m < 64; m <<= 1) acc += __shfl_xor(acc, m);
  __shared__ float w[4];
  if ((threadIdx.x & 63) == 0) w[threadIdx.x >> 6] = acc;
  __syncthreads();
  if (threadIdx.x == 0)
    atomicAdd(out, (w[0] + w[1] + w[2] + w[3]) * (1.0f / (float)NROWS));
}

// ---------------------------------------------------------------------------
extern "C" void kernel_launch(void* const* d_in, const int* in_sizes, int n_in,
                              void* d_out, int out_size, void* d_ws, size_t ws_size,
                              hipStream_t stream) {
  const float* h  = (const float*)d_in[0];
  const float* hg = (const float*)d_in[1];

  char* ws = (char*)d_ws;
  const size_t OFF_QS   = 0;                      // 2 MB (8192*256 fp8)
  const size_t OFF_KEYS = (size_t)2 << 20;        // 4 MB (16384*256 fp8)
  const size_t OFF_P    = (size_t)6 << 20;        // 32 KB
  const size_t OFF_DIAG = OFF_P + 32 * 1024;      // 32 KB
  const size_t OFF_S    = OFF_DIAG + 32 * 1024;   // 32 KB
  const size_t NEED     = OFF_S + 32 * 1024;
  if (ws_size < NEED) return;

  unsigned int* qs8   = (unsigned int*)(ws + OFF_QS);
  unsigned int* keys8 = (unsigned int*)(ws + OFF_KEYS);
  float* Pterm   = (float*)(ws + OFF_P);
  float* diagsub = (float*)(ws + OFF_DIAG);
  float* S       = (float*)(ws + OFF_S);

  prep_kernel<<<2048, 256, 0, stream>>>(h, hg, qs8, keys8, Pterm, diagsub, S,
                                        (float*)d_out);
  nce_gemm<<<512, 512, 0, stream>>>(qs8, keys8, S);
  finalize_kernel<<<32, 256, 0, stream>>>(S, Pterm, diagsub, (float*)d_out);
}

// Round 19
// 55.533 us; speedup vs baseline: 2.9794x; 2.9794x over previous
//
#include <hip/hip_runtime.h>

// ---------- types ----------
typedef __attribute__((ext_vector_type(4))) float float4_;
typedef __attribute__((ext_vector_type(4))) float f32x4;
typedef __attribute__((ext_vector_type(8))) int   i32x8;

#define NROWS 8192
#define NKEYS 16384
#define DDIM  256

// exp(x/T) == exp2(x * C_SC)
static constexpr float T_INV = (float)(1.0 / 0.07);
static constexpr float C_SC  = (float)(1.0 / (0.07 * 0.6931471805599453));

// ---------------------------------------------------------------------------
// Fragment-linear key layout (NO LDS, NO swizzle): key-group G = 16 keys.
// Byte address of the 32B B-fragment of (G, kk, lane):
//     G*4096 + kk*2048 + lane*32
// lane = l4*16 + l15 holds key (G*16 + l15), dims [kk*128 + l4*32, +32)
// — the 16x16x128 B operand convention verified r8-r15.
// prep writes it, gemm reads it (rule #21: one convention, both sides).
// ---------------------------------------------------------------------------

// ---------------------------------------------------------------------------
// Kernel 1: normalize rows; emit fp8 e4m3 (OCP, HW cvt):
//   qs8  [8192][256] fp8: normalized q scaled by C_SC (MFMA A), natural.
//   keys8: fragment-linear (above). Keys 0..8191 = q, 8192..16383 = g.
//   Pterm[row] = dot_f32(q,g)/T ; diagsub[row] = exp2 of fp8-level qq diag.
// Also zeroes S and out[0].
// ---------------------------------------------------------------------------
__global__ __launch_bounds__(256) void prep_kernel(
    const float* __restrict__ h, const float* __restrict__ g,
    unsigned int* __restrict__ qs8, unsigned int* __restrict__ keys8,
    float* __restrict__ Pterm, float* __restrict__ diagsub,
    float* __restrict__ S, float* __restrict__ out)
{
  const int row  = blockIdx.x * 4 + (threadIdx.x >> 6);
  const int lane = threadIdx.x & 63;       // 4 dims each
  float4_ hv = *((const float4_*)h + row * 64 + lane);
  float4_ gv = *((const float4_*)g + row * 64 + lane);

  float ssh = hv.x*hv.x + hv.y*hv.y + hv.z*hv.z + hv.w*hv.w;
  float ssg = gv.x*gv.x + gv.y*gv.y + gv.z*gv.z + gv.w*gv.w;
#pragma unroll
  for (int m = 1; m < 64; m <<= 1) {
    ssh += __shfl_xor(ssh, m);
    ssg += __shfl_xor(ssg, m);
  }
  const float sh = 1.0f / fmaxf(sqrtf(ssh), 1e-8f);
  const float sg = 1.0f / fmaxf(sqrtf(ssg), 1e-8f);

  float qn[4] = { hv.x*sh, hv.y*sh, hv.z*sh, hv.w*sh };
  float gn[4] = { gv.x*sg, gv.y*sg, gv.z*sg, gv.w*sg };

  float pd = qn[0]*gn[0] + qn[1]*gn[1] + qn[2]*gn[2] + qn[3]*gn[3];

  // fp8 packs (RNE, saturating). word_sel / byte_sel must be literals.
  int pq = __builtin_amdgcn_cvt_pk_fp8_f32(qn[0], qn[1], 0, 0);
  pq     = __builtin_amdgcn_cvt_pk_fp8_f32(qn[2], qn[3], pq, 1);
  int ps = __builtin_amdgcn_cvt_pk_fp8_f32(qn[0]*C_SC, qn[1]*C_SC, 0, 0);
  ps     = __builtin_amdgcn_cvt_pk_fp8_f32(qn[2]*C_SC, qn[3]*C_SC, ps, 1);
  int pg = __builtin_amdgcn_cvt_pk_fp8_f32(gn[0], gn[1], 0, 0);
  pg     = __builtin_amdgcn_cvt_pk_fp8_f32(gn[2], gn[3], pg, 1);

  float dd =
      __builtin_amdgcn_cvt_f32_fp8(ps, 0) * __builtin_amdgcn_cvt_f32_fp8(pq, 0)
    + __builtin_amdgcn_cvt_f32_fp8(ps, 1) * __builtin_amdgcn_cvt_f32_fp8(pq, 1)
    + __builtin_amdgcn_cvt_f32_fp8(ps, 2) * __builtin_amdgcn_cvt_f32_fp8(pq, 2)
    + __builtin_amdgcn_cvt_f32_fp8(ps, 3) * __builtin_amdgcn_cvt_f32_fp8(pq, 3);

#pragma unroll
  for (int m = 1; m < 64; m <<= 1) {
    pd += __shfl_xor(pd, m);
    dd += __shfl_xor(dd, m);
  }

  qs8[(size_t)row * 64 + lane] = (unsigned int)ps;   // natural, coalesced

  // fragment-linear key writes: this lane's dword = dims [lane*4, lane*4+4)
  // kk = lane>>5 ; l4 = (lane>>3)&3 ; inner byte = (lane&7)*4
  char* kb = (char*)keys8;
  const int foff = ((lane >> 5) << 11) + (((lane >> 3) & 3) << 9)
                 + ((lane & 7) << 2);
  {
    const int k = row;                     // q keys
    *(unsigned int*)(kb + (((size_t)(k >> 4)) << 12) + foff
                     + ((k & 15) << 5)) = (unsigned int)pq;
  }
  {
    const int k = NROWS + row;             // g keys
    *(unsigned int*)(kb + (((size_t)(k >> 4)) << 12) + foff
                     + ((k & 15) << 5)) = (unsigned int)pg;
  }

  if (lane == 0) {
    Pterm[row]   = pd * T_INV;
    diagsub[row] = __builtin_amdgcn_exp2f(dd);
    S[row]       = 0.0f;
    if (row == 0) out[0] = 0.0f;           // finalize accumulates atomically
  }
}

// ---------------------------------------------------------------------------
// Kernel 2: fused MX-fp8 GEMM (K=128/instr) + exp2 + row-sum — no LDS
// staging, no main-loop barriers (r13 structure), BM=64, grid 512.
// vs r18 (spilled at VGPR=64, WRITE 372MB — prefetch never tested): DEPTH-2
// prefetch via a 3-slot rotating buffer in a FULLY-UNROLLED loop. All
// indices (g%3) compile-time (rule #20); rotation = SSA renaming, no
// loop-carried copies; no conditionals holding live regs. launch_bounds
// (512,1): allocator unconstrained (~165 regs), occupancy 1 block/CU —
// r15 proved TLP is null (phase-locked waves all stall on loads together);
// the fix is removing the load-wait from every wave's path: loads for
// group g+2 issue ~550cy before use, so the counted vmcnt is free.
// ---------------------------------------------------------------------------
__global__ __launch_bounds__(512, 1) void nce_gemm(
    const unsigned int* __restrict__ qs8,
    const unsigned int* __restrict__ keys8,
    float* __restrict__ S)
{
  __shared__ float sred[64];               // end-of-kernel reduce only

  const int tid  = threadIdx.x;
  const int wid  = tid >> 6;
  const int lane = tid & 63;
  const int l15  = lane & 15, l4 = lane >> 4;

  const int bid   = blockIdx.x;
  const int slice = bid & 3;               // constant per XCD
  const int mtile = bid >> 2;              // 0..127
  const int m0    = mtile * 64;            // all 8 waves share these 64 rows

  if (tid < 64) sred[tid] = 0.0f;

  // ---- A fragments: 4 mf x 2 kk x 32B ; K elem = kk*128 + l4*32 + j ----
  const char* qb = (const char*)qs8;
  i32x8 a8[4][2];
#pragma unroll
  for (int mf = 0; mf < 4; ++mf) {
    const char* rp = qb + (size_t)(m0 + mf * 16 + l15) * 256 + l4 * 32;
#pragma unroll
    for (int kk = 0; kk < 2; ++kk)
      a8[mf][kk] = *(const i32x8*)(rp + kk * 128);
  }

  const f32x4 zero4 = { 0.f, 0.f, 0.f, 0.f };
  f32x4 acc[4];
  float Sp[4][4] = {};                     // [mf][q] row-sums

  // wave's private key range: 512 keys = 32 groups of 16
  const char* kp = (const char*)keys8
      + (((size_t)(slice * 256 + wid * 32)) << 12) + (size_t)lane * 32;

  // ---- depth-2 software pipeline: 3-slot rotating B buffer ----
  i32x8 b0[3], b1[3];
  b0[0] = *(const i32x8*)(kp);
  b1[0] = *(const i32x8*)(kp + 2048);
  b0[1] = *(const i32x8*)(kp + 4096);
  b1[1] = *(const i32x8*)(kp + 4096 + 2048);

#pragma unroll
  for (int g = 0; g < 32; ++g) {
    if (g + 2 < 32) {                      // prefetch g+2 (compile-time slot)
      b0[(g + 2) % 3] = *(const i32x8*)(kp + ((size_t)(g + 2) << 12));
      b1[(g + 2) % 3] = *(const i32x8*)(kp + ((size_t)(g + 2) << 12) + 2048);
    }

    if (g > 0) {                           // harvest prev group (VALU)
#pragma unroll
      for (int mf = 0; mf < 4; ++mf)
#pragma unroll
        for (int q = 0; q < 4; ++q)
          Sp[mf][q] += __builtin_amdgcn_exp2f(acc[mf][q]);
    }

    // MFMAs consume slot g%3 (loaded two iterations ago — latency hidden).
    // cbsz=0 (A fmt fp8 e4m3), blgp=0 (B fmt fp8), scales 127 = x1.0
#pragma unroll
    for (int mf = 0; mf < 4; ++mf) {
      f32x4 t = __builtin_amdgcn_mfma_scale_f32_16x16x128_f8f6f4(
          a8[mf][0], b0[g % 3], zero4, 0, 0, 0, 127, 0, 127);
      acc[mf] = __builtin_amdgcn_mfma_scale_f32_16x16x128_f8f6f4(
          a8[mf][1], b1[g % 3], t, 0, 0, 0, 127, 0, 127);
    }
  }
#pragma unroll
  for (int mf = 0; mf < 4; ++mf)           // last group's harvest
#pragma unroll
    for (int q = 0; q < 4; ++q)
      Sp[mf][q] += __builtin_amdgcn_exp2f(acc[mf][q]);

  // reduce across the 16 key-columns (lanes sharing l4)
#pragma unroll
  for (int mf = 0; mf < 4; ++mf)
#pragma unroll
    for (int q = 0; q < 4; ++q) {
      float v = Sp[mf][q];
      v += __shfl_xor(v, 1); v += __shfl_xor(v, 2);
      v += __shfl_xor(v, 4); v += __shfl_xor(v, 8);
      Sp[mf][q] = v;
    }

  // block-level reduce in LDS (8 waves share the same 64 rows), then
  // one global atomic per row (4 slices -> 4 atomics/row total).
  __syncthreads();                         // sred init visible
  if (l15 == 0) {
#pragma unroll
    for (int mf = 0; mf < 4; ++mf)
#pragma unroll
      for (int q = 0; q < 4; ++q)
        atomicAdd(&sred[mf * 16 + l4 * 4 + q], Sp[mf][q]);
  }
  __syncthreads();
  if (tid < 64) atomicAdd(&S[m0 + tid], sred[tid]);
}

// ---------------------------------------------------------------------------
// Kernel 3: loss partials -> atomicAdd(out). 32 blocks x 256 thr = 1 row/thr.
// ---------------------------------------------------------------------------
__global__ __launch_bounds__(256) void finalize_kernel(
    const float* __restrict__ S, const float* __restrict__ Pterm,
    const float* __restrict__ diagsub, float* __restrict__ out)
{
  const int i = blockIdx.x * 256 + threadIdx.x;
  float v = S[i] - diagsub[i];
  float acc = logf(fmaxf(v, 1e-20f)) - Pterm[i];
#pragma unroll
  for (int m = 1; m < 64; m <<= 1) acc += __shfl_xor(acc, m);
  __shared__ float w[4];
  if ((threadIdx.x & 63) == 0) w[threadIdx.x >> 6] = acc;
  __syncthreads();
  if (threadIdx.x == 0)
    atomicAdd(out, (w[0] + w[1] + w[2] + w[3]) * (1.0f / (float)NROWS));
}

// ---------------------------------------------------------------------------
extern "C" void kernel_launch(void* const* d_in, const int* in_sizes, int n_in,
                              void* d_out, int out_size, void* d_ws, size_t ws_size,
                              hipStream_t stream) {
  const float* h  = (const float*)d_in[0];
  const float* hg = (const float*)d_in[1];

  char* ws = (char*)d_ws;
  const size_t OFF_QS   = 0;                      // 2 MB (8192*256 fp8)
  const size_t OFF_KEYS = (size_t)2 << 20;        // 4 MB (16384*256 fp8)
  const size_t OFF_P    = (size_t)6 << 20;        // 32 KB
  const size_t OFF_DIAG = OFF_P + 32 * 1024;      // 32 KB
  const size_t OFF_S    = OFF_DIAG + 32 * 1024;   // 32 KB
  const size_t NEED     = OFF_S + 32 * 1024;
  if (ws_size < NEED) return;

  unsigned int* qs8   = (unsigned int*)(ws + OFF_QS);
  unsigned int* keys8 = (unsigned int*)(ws + OFF_KEYS);
  float* Pterm   = (float*)(ws + OFF_P);
  float* diagsub = (float*)(ws + OFF_DIAG);
  float* S       = (float*)(ws + OFF_S);

  prep_kernel<<<2048, 256, 0, stream>>>(h, hg, qs8, keys8, Pterm, diagsub, S,
                                        (float*)d_out);
  nce_gemm<<<512, 512, 0, stream>>>(qs8, keys8, S);
  finalize_kernel<<<32, 256, 0, stream>>>(S, Pterm, diagsub, (float*)d_out);
}